// Round 1
// baseline (98.146 us; speedup 1.0000x reference)
//
#include <hip/hip_runtime.h>

// u_dot_v: score[e] = dot(feat[src[e]], feat[dst[e]]), D_FEAT = 32.
// 8 lanes per edge, each lane handles one float4 (16 B) of the 128 B row.
// A wave (64 lanes) covers 8 edges; each gather instruction touches 8
// fully-consumed 128 B cache lines. Shuffle-reduce within 8-lane groups.

#define D_FEAT 32

__global__ __launch_bounds__(256) void edge_dot_kernel(
    const float* __restrict__ feat,
    const int*   __restrict__ src,
    const int*   __restrict__ dst,
    float*       __restrict__ out,
    int n_edges)
{
    const int lane8 = threadIdx.x & 7;                    // lane within edge group
    const int tid   = blockIdx.x * blockDim.x + threadIdx.x;
    const int edges_per_pass = (gridDim.x * blockDim.x) >> 3;

    for (int e = tid >> 3; e < n_edges; e += edges_per_pass) {
        const int s = src[e];
        const int d = dst[e];
        const float4 a = *reinterpret_cast<const float4*>(
            feat + (size_t)s * D_FEAT + lane8 * 4);
        const float4 b = *reinterpret_cast<const float4*>(
            feat + (size_t)d * D_FEAT + lane8 * 4);
        float p = a.x * b.x + a.y * b.y + a.z * b.z + a.w * b.w;
        // reduce across the 8 lanes of this edge group
        p += __shfl_xor(p, 1, 8);
        p += __shfl_xor(p, 2, 8);
        p += __shfl_xor(p, 4, 8);
        if (lane8 == 0) out[e] = p;
    }
}

extern "C" void kernel_launch(void* const* d_in, const int* in_sizes, int n_in,
                              void* d_out, int out_size, void* d_ws, size_t ws_size,
                              hipStream_t stream) {
    const float* feat = (const float*)d_in[0];
    const int*   src  = (const int*)d_in[1];
    const int*   dst  = (const int*)d_in[2];
    float*       out  = (float*)d_out;
    const int n_edges = in_sizes[1];

    const int block = 256;
    // Fill the machine (256 CU x 2048 threads = 524288) and grid-stride.
    int grid = (n_edges * 8 + block - 1) / block;
    if (grid > 2048) grid = 2048;

    edge_dot_kernel<<<grid, block, 0, stream>>>(feat, src, dst, out, n_edges);
}

// Round 2
// 97.163 us; speedup vs baseline: 1.0101x; 1.0101x over previous
//
#include <hip/hip_runtime.h>

// u_dot_v: score[e] = dot(feat[src[e]], feat[dst[e]]), D_FEAT = 32 (128 B/row).
// 8 lanes per edge; each group of 8 lanes processes FOUR consecutive edges per
// iteration:
//   - src/dst indices for the 4 edges load as one int4 each (wave-wide: one
//     contiguous 128 B line per index-load instruction)
//   - 8 independent float4 gathers issue back-to-back (MLP = 8/thread)
//   - results store as one coalesced float4 per group
// Gather instructions touch 8 fully-consumed 128 B rows each (no over-fetch).

#define D_FEAT 32

__global__ __launch_bounds__(256) void edge_dot4_kernel(
    const float* __restrict__ feat,
    const int*   __restrict__ src,
    const int*   __restrict__ dst,
    float*       __restrict__ out,
    int n_edges)
{
    const int lane8   = threadIdx.x & 7;
    const int off     = lane8 * 4;
    const int gid     = (blockIdx.x * blockDim.x + threadIdx.x) >> 3;
    const int ngroups = (gridDim.x * blockDim.x) >> 3;
    const int nquads  = n_edges >> 2;

    for (int q = gid; q < nquads; q += ngroups) {
        const int e = q * 4;
        const int4 s4 = *reinterpret_cast<const int4*>(src + e);
        const int4 d4 = *reinterpret_cast<const int4*>(dst + e);

        const float4 a0 = *reinterpret_cast<const float4*>(feat + (size_t)s4.x * D_FEAT + off);
        const float4 a1 = *reinterpret_cast<const float4*>(feat + (size_t)s4.y * D_FEAT + off);
        const float4 a2 = *reinterpret_cast<const float4*>(feat + (size_t)s4.z * D_FEAT + off);
        const float4 a3 = *reinterpret_cast<const float4*>(feat + (size_t)s4.w * D_FEAT + off);
        const float4 b0 = *reinterpret_cast<const float4*>(feat + (size_t)d4.x * D_FEAT + off);
        const float4 b1 = *reinterpret_cast<const float4*>(feat + (size_t)d4.y * D_FEAT + off);
        const float4 b2 = *reinterpret_cast<const float4*>(feat + (size_t)d4.z * D_FEAT + off);
        const float4 b3 = *reinterpret_cast<const float4*>(feat + (size_t)d4.w * D_FEAT + off);

        float p0 = a0.x * b0.x + a0.y * b0.y + a0.z * b0.z + a0.w * b0.w;
        float p1 = a1.x * b1.x + a1.y * b1.y + a1.z * b1.z + a1.w * b1.w;
        float p2 = a2.x * b2.x + a2.y * b2.y + a2.z * b2.z + a2.w * b2.w;
        float p3 = a3.x * b3.x + a3.y * b3.y + a3.z * b3.z + a3.w * b3.w;

        p0 += __shfl_xor(p0, 1, 8);
        p1 += __shfl_xor(p1, 1, 8);
        p2 += __shfl_xor(p2, 1, 8);
        p3 += __shfl_xor(p3, 1, 8);
        p0 += __shfl_xor(p0, 2, 8);
        p1 += __shfl_xor(p1, 2, 8);
        p2 += __shfl_xor(p2, 2, 8);
        p3 += __shfl_xor(p3, 2, 8);
        p0 += __shfl_xor(p0, 4, 8);
        p1 += __shfl_xor(p1, 4, 8);
        p2 += __shfl_xor(p2, 4, 8);
        p3 += __shfl_xor(p3, 4, 8);

        if (lane8 == 0) {
            *reinterpret_cast<float4*>(out + e) = make_float4(p0, p1, p2, p3);
        }
    }

    // tail (n_edges not divisible by 4)
    for (int e = nquads * 4 + gid; e < n_edges; e += ngroups) {
        const int s = src[e];
        const int d = dst[e];
        const float4 a = *reinterpret_cast<const float4*>(feat + (size_t)s * D_FEAT + off);
        const float4 b = *reinterpret_cast<const float4*>(feat + (size_t)d * D_FEAT + off);
        float p = a.x * b.x + a.y * b.y + a.z * b.z + a.w * b.w;
        p += __shfl_xor(p, 1, 8);
        p += __shfl_xor(p, 2, 8);
        p += __shfl_xor(p, 4, 8);
        if (lane8 == 0) out[e] = p;
    }
}

extern "C" void kernel_launch(void* const* d_in, const int* in_sizes, int n_in,
                              void* d_out, int out_size, void* d_ws, size_t ws_size,
                              hipStream_t stream) {
    const float* feat = (const float*)d_in[0];
    const int*   src  = (const int*)d_in[1];
    const int*   dst  = (const int*)d_in[2];
    float*       out  = (float*)d_out;
    const int n_edges = in_sizes[1];

    const int block = 256;
    int grid = 2048;  // 65536 groups of 8 lanes; ~10 unrolled iterations each

    edge_dot4_kernel<<<grid, block, 0, stream>>>(feat, src, dst, out, n_edges);
}

// Round 4
// 95.660 us; speedup vs baseline: 1.0260x; 1.0157x over previous
//
#include <hip/hip_runtime.h>

// u_dot_v: score[e] = dot(feat[src[e]], feat[dst[e]]), D_FEAT = 32 (128 B/row).
// 8 lanes per edge, one quad of edges per 8-lane group, exact-cover grid.
// Index loads and output stores are NONTEMPORAL (clang ext_vector_type, since
// the builtin rejects HIP_vector_type) so the 20 MB index stream and 10 MB
// output stream don't evict feat rows from L2 — all 32 MB of aggregate L2
// serves the random 128 B row gathers (the bottleneck traffic).

#define D_FEAT 32

typedef int   v4i __attribute__((ext_vector_type(4)));
typedef float v4f __attribute__((ext_vector_type(4)));

__global__ __launch_bounds__(256) void edge_dot_nt_kernel(
    const float* __restrict__ feat,
    const int*   __restrict__ src,
    const int*   __restrict__ dst,
    float*       __restrict__ out,
    int n_edges)
{
    const int lane8 = threadIdx.x & 7;
    const int off   = lane8 * 4;
    const int gid   = (blockIdx.x * blockDim.x + threadIdx.x) >> 3;
    const int nquads = n_edges >> 2;

    if (gid < nquads) {
        const int e = gid * 4;
        const v4i s4 = __builtin_nontemporal_load(reinterpret_cast<const v4i*>(src + e));
        const v4i d4 = __builtin_nontemporal_load(reinterpret_cast<const v4i*>(dst + e));

        const v4f a0 = *reinterpret_cast<const v4f*>(feat + (size_t)s4.x * D_FEAT + off);
        const v4f a1 = *reinterpret_cast<const v4f*>(feat + (size_t)s4.y * D_FEAT + off);
        const v4f a2 = *reinterpret_cast<const v4f*>(feat + (size_t)s4.z * D_FEAT + off);
        const v4f a3 = *reinterpret_cast<const v4f*>(feat + (size_t)s4.w * D_FEAT + off);
        const v4f b0 = *reinterpret_cast<const v4f*>(feat + (size_t)d4.x * D_FEAT + off);
        const v4f b1 = *reinterpret_cast<const v4f*>(feat + (size_t)d4.y * D_FEAT + off);
        const v4f b2 = *reinterpret_cast<const v4f*>(feat + (size_t)d4.z * D_FEAT + off);
        const v4f b3 = *reinterpret_cast<const v4f*>(feat + (size_t)d4.w * D_FEAT + off);

        float p0 = a0.x * b0.x + a0.y * b0.y + a0.z * b0.z + a0.w * b0.w;
        float p1 = a1.x * b1.x + a1.y * b1.y + a1.z * b1.z + a1.w * b1.w;
        float p2 = a2.x * b2.x + a2.y * b2.y + a2.z * b2.z + a2.w * b2.w;
        float p3 = a3.x * b3.x + a3.y * b3.y + a3.z * b3.z + a3.w * b3.w;

        p0 += __shfl_xor(p0, 1, 8);
        p1 += __shfl_xor(p1, 1, 8);
        p2 += __shfl_xor(p2, 1, 8);
        p3 += __shfl_xor(p3, 1, 8);
        p0 += __shfl_xor(p0, 2, 8);
        p1 += __shfl_xor(p1, 2, 8);
        p2 += __shfl_xor(p2, 2, 8);
        p3 += __shfl_xor(p3, 2, 8);
        p0 += __shfl_xor(p0, 4, 8);
        p1 += __shfl_xor(p1, 4, 8);
        p2 += __shfl_xor(p2, 4, 8);
        p3 += __shfl_xor(p3, 4, 8);

        if (lane8 == 0) {
            v4f r; r.x = p0; r.y = p1; r.z = p2; r.w = p3;
            __builtin_nontemporal_store(r, reinterpret_cast<v4f*>(out + e));
        }
    } else if (gid == nquads) {
        // tail: up to 3 edges, handled serially by the one extra group
        for (int e = nquads * 4; e < n_edges; ++e) {
            const int s = __builtin_nontemporal_load(src + e);
            const int d = __builtin_nontemporal_load(dst + e);
            const v4f a = *reinterpret_cast<const v4f*>(feat + (size_t)s * D_FEAT + off);
            const v4f b = *reinterpret_cast<const v4f*>(feat + (size_t)d * D_FEAT + off);
            float p = a.x * b.x + a.y * b.y + a.z * b.z + a.w * b.w;
            p += __shfl_xor(p, 1, 8);
            p += __shfl_xor(p, 2, 8);
            p += __shfl_xor(p, 4, 8);
            if (lane8 == 0) __builtin_nontemporal_store(p, out + e);
        }
    }
}

extern "C" void kernel_launch(void* const* d_in, const int* in_sizes, int n_in,
                              void* d_out, int out_size, void* d_ws, size_t ws_size,
                              hipStream_t stream) {
    const float* feat = (const float*)d_in[0];
    const int*   src  = (const int*)d_in[1];
    const int*   dst  = (const int*)d_in[2];
    float*       out  = (float*)d_out;
    const int n_edges = in_sizes[1];

    const int block = 256;
    const int nquads = n_edges >> 2;
    const int ngroups = nquads + ((n_edges & 3) ? 1 : 0);   // 8-lane groups needed
    const int grid = (ngroups * 8 + block - 1) / block;     // exact cover

    edge_dot_nt_kernel<<<grid, block, 0, stream>>>(feat, src, dst, out, n_edges);
}